// Round 4
// baseline (378.772 us; speedup 1.0000x reference)
//
#include <hip/hip_runtime.h>
#include <hip/hip_bf16.h>

// Problem: B=8, S=4096, D=768
//   y = tanh(x @ W); scores = y . v; w = softmax_S(scores); out = sum_s w * x
constexpr int Bb = 8;
constexpr int Ss = 4096;
constexpr int Dd = 768;
constexpr int Mm = Bb * Ss;      // 32768 rows

typedef __bf16 bf16x8 __attribute__((ext_vector_type(8)));
typedef float f32x4 __attribute__((ext_vector_type(4)));

__device__ __forceinline__ float fast_tanh(float x) {
    return 1.f - 2.f / (__expf(2.f * x) + 1.f);
}

// async global->LDS, 16B per lane. LDS dest is wave-uniform base + lane*16;
// our layouts are strictly linear in t so this holds.
__device__ __forceinline__ void load_lds16(const void* g, void* l) {
    __builtin_amdgcn_global_load_lds(
        (const __attribute__((address_space(1))) unsigned int*)g,
        (__attribute__((address_space(3))) unsigned int*)l, 16, 0, 0);
}

// ---------------- Kernel 0: W[k][n] fp32 -> Wt[n][k] bf16 (LDS-tiled transpose)
__global__ __launch_bounds__(256) void convW(const float* __restrict__ W,
                                             __bf16* __restrict__ Wt) {
    __shared__ float tile[32][33];
    const int tx = threadIdx.x & 31;
    const int ty = threadIdx.x >> 5;
    const int kb = blockIdx.x * 32;
    const int nb = blockIdx.y * 32;
#pragma unroll
    for (int i = 0; i < 32; i += 8)
        tile[ty + i][tx] = W[(size_t)(kb + ty + i) * Dd + nb + tx];
    __syncthreads();
#pragma unroll
    for (int i = 0; i < 32; i += 8)
        Wt[(size_t)(nb + ty + i) * Dd + kb + tx] = (__bf16)tile[tx][ty + i];
}

// ---------------- Kernel 1: scores[m] += sum_n v[n]*tanh( (x@W)[m][n] )
// m97-style: 128x128 tile, BK=32, 256 threads (4 waves, 2x2 of 64x64).
// Both operands staged per k-step via global_load_lds (A fp32 16KB, B bf16 8KB),
// fragments via ds_read_b128; A converted fp32->bf16 at fragment read.
// grid = (6 n-tiles, 256 m-tiles) = 1536 blocks (~6/CU -> cross-block overlap).
__global__ __launch_bounds__(256) void scores_gemm(
    const float* __restrict__ x, const __bf16* __restrict__ Wt,
    const float* __restrict__ v, float* __restrict__ scores) {
    __shared__ float As[128 * 32];       // 16 KB, row-major 128 rows x 32 f32
    __shared__ __bf16 Bs[128 * 32];      // 8 KB, row-major 128 cols x 32 bf16
    __shared__ float ssc[2][128];

    const int t = threadIdx.x;
    const int nb = blockIdx.x;           // 0..5
    const int mb = blockIdx.y;           // 0..255
    const int lane = t & 63;
    const int wave = t >> 6;
    const int wm = wave >> 1;
    const int wn = wave & 1;
    const int quad = lane >> 4;
    const int lid = lane & 15;

    // staging pointers: A tile = 16KB -> 4 x 16B per thread; B tile = 8KB -> 2 x 16B
    const float* ag[4]; float* al[4];
#pragma unroll
    for (int j = 0; j < 4; ++j) {
        const int flat = j * 4096 + t * 16;      // byte offset in A tile
        const int row = flat >> 7;               // 128 B per row (32 f32)
        const int colb = flat & 127;
        ag[j] = x + (size_t)(mb * 128 + row) * Dd + (colb >> 2);
        al[j] = &As[flat >> 2];
    }
    const __bf16* bg[2]; __bf16* bl[2];
#pragma unroll
    for (int j = 0; j < 2; ++j) {
        const int flat = j * 4096 + t * 16;      // byte offset in B tile
        const int row = flat >> 6;               // 64 B per row (32 bf16)
        const int colb = flat & 63;
        bg[j] = Wt + (size_t)(nb * 128 + row) * Dd + (colb >> 1);
        bl[j] = &Bs[flat >> 1];
    }

    f32x4 acc[4][4];
#pragma unroll
    for (int i = 0; i < 4; ++i)
#pragma unroll
        for (int j = 0; j < 4; ++j) acc[i][j] = (f32x4){0.f, 0.f, 0.f, 0.f};

    for (int kb = 0; kb < 24; ++kb) {
        // stage k-slab kb (A: +32 f32 per kstep, B: +32 bf16 per kstep)
#pragma unroll
        for (int j = 0; j < 4; ++j) load_lds16(ag[j] + kb * 32, al[j]);
#pragma unroll
        for (int j = 0; j < 2; ++j) load_lds16(bg[j] + kb * 32, bl[j]);
        __syncthreads();                          // drains vmcnt before barrier

        bf16x8 af[4], bfr[4];
#pragma unroll
        for (int tm = 0; tm < 4; ++tm) {
            const float* ap = &As[(wm * 64 + tm * 16 + lid) * 32 + quad * 8];
            const float4 lo = *(const float4*)ap;
            const float4 hi = *(const float4*)(ap + 4);
            bf16x8 a;
            a[0] = (__bf16)lo.x; a[1] = (__bf16)lo.y; a[2] = (__bf16)lo.z; a[3] = (__bf16)lo.w;
            a[4] = (__bf16)hi.x; a[5] = (__bf16)hi.y; a[6] = (__bf16)hi.z; a[7] = (__bf16)hi.w;
            af[tm] = a;
        }
#pragma unroll
        for (int tn = 0; tn < 4; ++tn)
            bfr[tn] = *(const bf16x8*)&Bs[(wn * 64 + tn * 16 + lid) * 32 + quad * 8];

#pragma unroll
        for (int tm = 0; tm < 4; ++tm)
#pragma unroll
            for (int tn = 0; tn < 4; ++tn)
                acc[tm][tn] = __builtin_amdgcn_mfma_f32_16x16x32_bf16(af[tm], bfr[tn], acc[tm][tn], 0, 0, 0);
        __syncthreads();                          // protect LDS before next stage
    }

    // epilogue: fold tanh * v over this block's 128 columns, reduce to rows
    float vv[4];
#pragma unroll
    for (int tn = 0; tn < 4; ++tn)
        vv[tn] = v[nb * 128 + wn * 64 + tn * 16 + lid];

#pragma unroll
    for (int tm = 0; tm < 4; ++tm)
#pragma unroll
        for (int r = 0; r < 4; ++r) {
            float s = 0.f;
#pragma unroll
            for (int tn = 0; tn < 4; ++tn) s += vv[tn] * fast_tanh(acc[tm][tn][r]);
            // C layout: col = lid, row = quad*4 + r
            s += __shfl_xor(s, 1);
            s += __shfl_xor(s, 2);
            s += __shfl_xor(s, 4);
            s += __shfl_xor(s, 8);
            if (lid == 0) ssc[wn][wm * 64 + tm * 16 + quad * 4 + r] = s;
        }
    __syncthreads();
    if (t < 128)
        atomicAdd(&scores[mb * 128 + t], ssc[0][t] + ssc[1][t]);
}

// ---------------- Kernel 2: softmax over S per batch row -> normalized weights
__global__ __launch_bounds__(256) void softmax_k(const float* __restrict__ scores,
                                                 float* __restrict__ weights) {
    const int b = blockIdx.x;
    const int t = threadIdx.x;
    const float* s = scores + (size_t)b * Ss;
    float* wgt = weights + (size_t)b * Ss;
    __shared__ float red[256];

    float mx = -1e30f;
    for (int i = t; i < Ss; i += 256) mx = fmaxf(mx, s[i]);
    red[t] = mx;
    __syncthreads();
    for (int o = 128; o > 0; o >>= 1) {
        if (t < o) red[t] = fmaxf(red[t], red[t + o]);
        __syncthreads();
    }
    mx = red[0];
    __syncthreads();
    float sum = 0.f;
    for (int i = t; i < Ss; i += 256) {
        const float e = __expf(s[i] - mx);
        wgt[i] = e;
        sum += e;
    }
    red[t] = sum;
    __syncthreads();
    for (int o = 128; o > 0; o >>= 1) {
        if (t < o) red[t] += red[t + o];
        __syncthreads();
    }
    const float inv = 1.f / red[0];
    for (int i = t; i < Ss; i += 256) wgt[i] *= inv;
}

// ---------------- Kernel 3a: per-chunk partial pool (NO atomics)
// grid = (64 chunks, B), 192 threads; partial[(b*64+c)*768 + d] = sum over 64 rows
__global__ __launch_bounds__(192) void pool1(const float* __restrict__ x,
                                             const float* __restrict__ weights,
                                             float* __restrict__ partial) {
    const int b = blockIdx.y;
    const int c = blockIdx.x;
    const int t = threadIdx.x;           // 0..191, owns float4 at d = t*4
    const float* base = x + ((size_t)b * Ss + c * 64) * Dd;
    const float* wrow = weights + (size_t)b * Ss + c * 64;
    float4 acc = make_float4(0.f, 0.f, 0.f, 0.f);
#pragma unroll 8
    for (int i = 0; i < 64; ++i) {
        const float ww = wrow[i];
        const float4 xv = *(const float4*)(base + (size_t)i * Dd + t * 4);
        acc.x += ww * xv.x;
        acc.y += ww * xv.y;
        acc.z += ww * xv.z;
        acc.w += ww * xv.w;
    }
    *(float4*)(partial + ((size_t)(b * 64 + c)) * Dd + t * 4) = acc;
}

// ---------------- Kernel 3b: out[b][d] = sum_c partial[b][c][d]
__global__ __launch_bounds__(768) void pool2(const float* __restrict__ partial,
                                             float* __restrict__ out) {
    const int b = blockIdx.x;
    const int d = threadIdx.x;           // 0..767
    float s = 0.f;
#pragma unroll 8
    for (int c = 0; c < 64; ++c) s += partial[((size_t)(b * 64 + c)) * Dd + d];
    out[(size_t)b * Dd + d] = s;
}

extern "C" void kernel_launch(void* const* d_in, const int* in_sizes, int n_in,
                              void* d_out, int out_size, void* d_ws, size_t ws_size,
                              hipStream_t stream) {
    (void)in_sizes; (void)n_in; (void)ws_size; (void)out_size;
    const float* x = (const float*)d_in[0];
    const float* v = (const float*)d_in[1];
    const float* W = (const float*)d_in[2];

    char* ws = (char*)d_ws;
    __bf16* Wt = (__bf16*)ws;                             // 1,179,648 B
    float* scores = (float*)(ws + 1179648);               //   131,072 B
    float* weights = (float*)(ws + 1179648 + 131072);     //   131,072 B
    float* partial = (float*)(ws + 1179648 + 262144);     // 1,572,864 B (8*64*768 f32)

    hipMemsetAsync(scores, 0, Mm * sizeof(float), stream);

    convW<<<dim3(Dd / 32, Dd / 32), 256, 0, stream>>>(W, Wt);
    scores_gemm<<<dim3(6, Mm / 128), 256, 0, stream>>>(x, Wt, v, scores);
    softmax_k<<<dim3(Bb), 256, 0, stream>>>(scores, weights);
    pool1<<<dim3(64, Bb), 192, 0, stream>>>(x, weights, partial);
    pool2<<<dim3(Bb), 768, 0, stream>>>(partial, (float*)d_out);
}

// Round 5
// 240.859 us; speedup vs baseline: 1.5726x; 1.5726x over previous
//
#include <hip/hip_runtime.h>
#include <hip/hip_bf16.h>

// Problem: B=8, S=4096, D=768
//   y = tanh(x @ W); scores = y . v; w = softmax_S(scores); out = sum_s w * x
constexpr int Bb = 8;
constexpr int Ss = 4096;
constexpr int Dd = 768;
constexpr int Mm = Bb * Ss;      // 32768 rows

typedef __bf16 bf16x8 __attribute__((ext_vector_type(8)));
typedef __bf16 bf16x4 __attribute__((ext_vector_type(4)));
typedef float f32x4 __attribute__((ext_vector_type(4)));

__device__ __forceinline__ float fast_tanh(float x) {
    return 1.f - 2.f / (__expf(2.f * x) + 1.f);
}

__device__ __forceinline__ void load_lds16(const void* g, void* l) {
    __builtin_amdgcn_global_load_lds(
        (const __attribute__((address_space(1))) unsigned int*)g,
        (__attribute__((address_space(3))) unsigned int*)l, 16, 0, 0);
}

// ---------------- Kernel 0: W[k][n] fp32 -> Wt[n][k] bf16 (LDS-tiled transpose)
__global__ __launch_bounds__(256) void convW(const float* __restrict__ W,
                                             __bf16* __restrict__ Wt) {
    __shared__ float tile[32][33];
    const int tx = threadIdx.x & 31;
    const int ty = threadIdx.x >> 5;
    const int kb = blockIdx.x * 32;
    const int nb = blockIdx.y * 32;
#pragma unroll
    for (int i = 0; i < 32; i += 8)
        tile[ty + i][tx] = W[(size_t)(kb + ty + i) * Dd + nb + tx];
    __syncthreads();
#pragma unroll
    for (int i = 0; i < 32; i += 8)
        Wt[(size_t)(nb + ty + i) * Dd + kb + tx] = (__bf16)tile[tx][ty + i];
}

// ---------------- Kernel 1: scores[m] += sum_n v[n]*tanh( (x@W)[m][n] )
// BM=64 x BN=384 tile, n-split 2 (score partial sums additive across n-blocks).
// 512 threads = 8 waves (2 wm x 4 wn); per wave 2 m-frags x 6 n-frags, acc=48 VGPR.
// K streamed in 24 steps of 32. A: register-staged fp32->bf16 (swizzle-free 64B
// stride). B: global_load_lds width=16 from L2-resident Wt. Double-buffered LDS,
// ONE barrier per kstep; prefetch issued right after barrier so the vmcnt drain
// at the next barrier waits on compute-phase-old loads. 57KB LDS -> 2 blocks/CU.
__global__ __launch_bounds__(512, 4) void scores_gemm(
    const float* __restrict__ x, const __bf16* __restrict__ Wt,
    const float* __restrict__ v, float* __restrict__ scores) {
    __shared__ __bf16 As[2][64 * 32];     // 2 x 4 KB
    __shared__ __bf16 Bs[2][384 * 32];    // 2 x 24 KB
    __shared__ float ssc[8][32];

    const int t = threadIdx.x;
    const int nb = blockIdx.x;            // 0..1
    const int mb = blockIdx.y;            // 0..511
    const int lane = t & 63;
    const int wave = t >> 6;
    const int wm = wave >> 2;             // 0..1 (32-row half)
    const int wn = wave & 3;              // 0..3 (96-col slice)
    const int quad = lane >> 4;
    const int lid = lane & 15;

    // A staging: thread t -> row t>>3, float4 c4 = t&7 (32 f32 per row-slab)
    const int arow = t >> 3;
    const int ac4 = t & 7;
    const float* agp = x + (size_t)(mb * 64 + arow) * Dd + ac4 * 4;

    // B staging: 3 x 16B per thread, flat j*8192 + t*16 bytes over [384 x 64B]
    const __bf16* bg[3];
    int bl[3];
#pragma unroll
    for (int j = 0; j < 3; ++j) {
        const int flat = j * 8192 + t * 16;
        const int col = flat >> 6;
        const int off = flat & 63;
        bg[j] = Wt + (size_t)(nb * 384 + col) * Dd + (off >> 1);
        bl[j] = flat >> 1;               // bf16 index into Bs[buf]
    }

    f32x4 acc[2][6];
#pragma unroll
    for (int tm = 0; tm < 2; ++tm)
#pragma unroll
        for (int nt = 0; nt < 6; ++nt) acc[tm][nt] = (f32x4){0.f, 0.f, 0.f, 0.f};

    // ---- prologue: stage kstep 0 into buf 0
    {
        const float4 a = *(const float4*)(agp);
        bf16x4 p;
        p[0] = (__bf16)a.x; p[1] = (__bf16)a.y; p[2] = (__bf16)a.z; p[3] = (__bf16)a.w;
        *(bf16x4*)(&As[0][arow * 32 + ac4 * 4]) = p;
#pragma unroll
        for (int j = 0; j < 3; ++j) load_lds16(bg[j], &Bs[0][bl[j]]);
    }

    for (int kb = 0; kb < 24; ++kb) {
        const int p = kb & 1;
        __syncthreads();                  // buf p staged; buf 1-p free

        float4 an;
        if (kb < 23) {
            an = *(const float4*)(agp + (kb + 1) * 32);     // issued now, used late
#pragma unroll
            for (int j = 0; j < 3; ++j)
                load_lds16(bg[j] + (kb + 1) * 32, &Bs[1 - p][bl[j]]);
        }

        bf16x8 af[2], bfr[6];
#pragma unroll
        for (int tm = 0; tm < 2; ++tm)
            af[tm] = *(const bf16x8*)(&As[p][(wm * 32 + tm * 16 + lid) * 32 + quad * 8]);
#pragma unroll
        for (int nt = 0; nt < 6; ++nt)
            bfr[nt] = *(const bf16x8*)(&Bs[p][(wn * 96 + nt * 16 + lid) * 32 + quad * 8]);

#pragma unroll
        for (int tm = 0; tm < 2; ++tm)
#pragma unroll
            for (int nt = 0; nt < 6; ++nt)
                acc[tm][nt] = __builtin_amdgcn_mfma_f32_16x16x32_bf16(af[tm], bfr[nt], acc[tm][nt], 0, 0, 0);

        if (kb < 23) {                    // convert + LDS write after MFMAs
            bf16x4 pa;
            pa[0] = (__bf16)an.x; pa[1] = (__bf16)an.y;
            pa[2] = (__bf16)an.z; pa[3] = (__bf16)an.w;
            *(bf16x4*)(&As[1 - p][arow * 32 + ac4 * 4]) = pa;
        }
    }

    // ---- epilogue: fold tanh*v over this block's 384 cols, reduce to rows
    float vv[6];
#pragma unroll
    for (int nt = 0; nt < 6; ++nt)
        vv[nt] = v[nb * 384 + wn * 96 + nt * 16 + lid];

#pragma unroll
    for (int tm = 0; tm < 2; ++tm)
#pragma unroll
        for (int r = 0; r < 4; ++r) {
            float s = 0.f;
#pragma unroll
            for (int nt = 0; nt < 6; ++nt) s += vv[nt] * fast_tanh(acc[tm][nt][r]);
            // C layout: col=lid, row=quad*4+r
            s += __shfl_xor(s, 1);
            s += __shfl_xor(s, 2);
            s += __shfl_xor(s, 4);
            s += __shfl_xor(s, 8);
            if (lid == 0) ssc[wave][tm * 16 + quad * 4 + r] = s;
        }
    __syncthreads();
    if (t < 64) {
        const int wmh = t >> 5;           // which 32-row half
        const int rl = t & 31;
        float s = 0.f;
#pragma unroll
        for (int ww = 0; ww < 4; ++ww) s += ssc[wmh * 4 + ww][rl];
        atomicAdd(&scores[mb * 64 + t], s);
    }
}

// ---------------- Kernel 2: softmax over S per batch row -> normalized weights
__global__ __launch_bounds__(256) void softmax_k(const float* __restrict__ scores,
                                                 float* __restrict__ weights) {
    const int b = blockIdx.x;
    const int t = threadIdx.x;
    const float* s = scores + (size_t)b * Ss;
    float* wgt = weights + (size_t)b * Ss;
    __shared__ float red[256];

    float mx = -1e30f;
    for (int i = t; i < Ss; i += 256) mx = fmaxf(mx, s[i]);
    red[t] = mx;
    __syncthreads();
    for (int o = 128; o > 0; o >>= 1) {
        if (t < o) red[t] = fmaxf(red[t], red[t + o]);
        __syncthreads();
    }
    mx = red[0];
    __syncthreads();
    float sum = 0.f;
    for (int i = t; i < Ss; i += 256) {
        const float e = __expf(s[i] - mx);
        wgt[i] = e;
        sum += e;
    }
    red[t] = sum;
    __syncthreads();
    for (int o = 128; o > 0; o >>= 1) {
        if (t < o) red[t] += red[t + o];
        __syncthreads();
    }
    const float inv = 1.f / red[0];
    for (int i = t; i < Ss; i += 256) wgt[i] *= inv;
}

// ---------------- Kernel 3a: per-chunk partial pool (no atomics)
// grid = (128 chunks, B) = 1024 blocks x 192 thr (4 blocks/CU, 12 waves/CU)
__global__ __launch_bounds__(192) void pool1(const float* __restrict__ x,
                                             const float* __restrict__ weights,
                                             float* __restrict__ partial) {
    const int b = blockIdx.y;
    const int c = blockIdx.x;            // 128 chunks x 32 rows
    const int t = threadIdx.x;           // owns float4 at d = t*4
    const float* base = x + ((size_t)b * Ss + c * 32) * Dd;
    const float* wrow = weights + (size_t)b * Ss + c * 32;
    float4 acc = make_float4(0.f, 0.f, 0.f, 0.f);
#pragma unroll 8
    for (int i = 0; i < 32; ++i) {
        const float ww = wrow[i];
        const float4 xv = *(const float4*)(base + (size_t)i * Dd + t * 4);
        acc.x += ww * xv.x;
        acc.y += ww * xv.y;
        acc.z += ww * xv.z;
        acc.w += ww * xv.w;
    }
    *(float4*)(partial + ((size_t)(b * 128 + c)) * Dd + t * 4) = acc;
}

// ---------------- Kernel 3b: out[b][d] = sum_c partial[b][c][d]
__global__ __launch_bounds__(768) void pool2(const float* __restrict__ partial,
                                             float* __restrict__ out) {
    const int b = blockIdx.x;
    const int d = threadIdx.x;           // 0..767
    float s = 0.f;
#pragma unroll 8
    for (int c = 0; c < 128; ++c) s += partial[((size_t)(b * 128 + c)) * Dd + d];
    out[(size_t)b * Dd + d] = s;
}

extern "C" void kernel_launch(void* const* d_in, const int* in_sizes, int n_in,
                              void* d_out, int out_size, void* d_ws, size_t ws_size,
                              hipStream_t stream) {
    (void)in_sizes; (void)n_in; (void)ws_size; (void)out_size;
    const float* x = (const float*)d_in[0];
    const float* v = (const float*)d_in[1];
    const float* W = (const float*)d_in[2];

    char* ws = (char*)d_ws;
    __bf16* Wt = (__bf16*)ws;                             // 1,179,648 B
    float* scores = (float*)(ws + 1179648);               //   131,072 B
    float* weights = (float*)(ws + 1179648 + 131072);     //   131,072 B
    float* partial = (float*)(ws + 1179648 + 262144);     // 3,145,728 B (8*128*768 f32)

    hipMemsetAsync(scores, 0, Mm * sizeof(float), stream);

    convW<<<dim3(Dd / 32, Dd / 32), 256, 0, stream>>>(W, Wt);
    scores_gemm<<<dim3(2, Mm / 64), 512, 0, stream>>>(x, Wt, v, scores);
    softmax_k<<<dim3(Bb), 256, 0, stream>>>(scores, weights);
    pool1<<<dim3(128, Bb), 192, 0, stream>>>(x, weights, partial);
    pool2<<<dim3(Bb), 768, 0, stream>>>(partial, (float*)d_out);
}